// Round 2
// baseline (102.341 us; speedup 1.0000x reference)
//
#include <hip/hip_runtime.h>

#define NBATCH 8192
#define NELEC  16
#define NMO    32
#define NCONF  64
#define NS     8          // NUP == NDOWN == 8
#define TSTR   20         // A (fp32) row stride in floats (80 B: 16B-aligned for b128)
#define TSZ    (NMO * TSTR)
#define TSTRH  24         // D (fp16) row stride in HALVES (48 B: 16B-aligned for b128)
#define TSZH   (NMO * TSTRH)

typedef float    v2f   __attribute__((ext_vector_type(2)));
typedef _Float16 half8 __attribute__((ext_vector_type(8)));
typedef _Float16 half4 __attribute__((ext_vector_type(4)));

__device__ __forceinline__ v2f pkfma(v2f a, v2f b, v2f c) {
#if __has_builtin(__builtin_elementwise_fma)
    return __builtin_elementwise_fma(a, b, c);
#else
    return a * b + c;
#endif
}
__device__ __forceinline__ v2f bc2(float s) { return (v2f){s, s}; }
__device__ __forceinline__ float getel2(const v2f (&R)[4], int j) {
    return (j & 1) ? R[j >> 1].y : R[j >> 1].x;
}
__device__ __forceinline__ void setel2(v2f (&R)[4], int j, float v) {
    if (j & 1) R[j >> 1].y = v; else R[j >> 1].x = v;
}

// R14: occupancy attack. R13 post-mortem: large DS restructure (sorted cols,
// spin-pure waves, vectorized staging) was NEUTRAL -> kernel is NOT
// DS-throughput-bound. Arithmetic floors (VALU ~6us, DS ~8us, HBM ~5.5us)
// are all far below the ~28us kernel -> latency/occupancy-bound. Estimated
// live set (A2=64 + y/x=32 + misc) was >128 VGPR -> 2 waves/SIMD (gfx950
// occupancy halves at 64/128/256). Diet:
//  (1) in-place back-sub (x overwrites y): -16 VGPR, identical arithmetic
//  (2) Batcher sort dropped (R13 proved it neutral): -60 VALU, -temps
//  (3) packed v_pk_fma trace accumulation: -32 scalar FMAs
//  (4) __launch_bounds__(256,4): force <=128 VGPR -> 4 waves/SIMD
// R11/R12 numerics stand: A fp32 (fp16-A amplified by kappa -> 4e8 fail);
// D fp16 fine (enters linearly). R8: gathers stay in LDS, not global.
__device__ __forceinline__ void solve8T(const float* __restrict__ MOT,
                                        const _Float16* __restrict__ D2T,
                                        const int (&cols)[NS], int eoff,
                                        float& det_out, float& tr_out)
{
    v2f A2[NS][4];                    // row j, pair p = cols {2p, 2p+1}
    #pragma unroll
    for (int j = 0; j < NS; ++j) {
        const float4* pa = (const float4*)(MOT + cols[j] * TSTR + eoff);
        float4 a0 = pa[0], a1 = pa[1];
        A2[j][0] = (v2f){a0.x, a0.y};
        A2[j][1] = (v2f){a0.z, a0.w};
        A2[j][2] = (v2f){a1.x, a1.y};
        A2[j][3] = (v2f){a1.z, a1.w};
    }

    // In-place LU, no pivot (packed over column pairs) — byte-identical to R7.
    float det = 1.0f;
    #pragma unroll
    for (int k = 0; k < NS; ++k) {
        float ukk = getel2(A2[k], k);
        det *= ukk;
        float pinv = __builtin_amdgcn_rcpf(ukk);
        #pragma unroll
        for (int r = k + 1; r < NS; ++r) {
            float m = getel2(A2[r], k) * pinv;
            v2f m2 = bc2(m);
            #pragma unroll
            for (int p = (k + 1) >> 1; p < 4; ++p)
                A2[r][p] = pkfma(-m2, A2[k][p], A2[r][p]);
            setel2(A2[r], k, m);
        }
        setel2(A2[k], k, pinv);
    }

    // tr = sum_k <x(k), row_k(D')>, k pairs in v2f lanes. z[] holds y then x
    // in place: back-sub step i reads z[i] (=y_i) exactly once before
    // overwriting with x_i; z[c2>i] are already x-values. -16 VGPR vs R13.
    v2f acc2 = (v2f){0.0f, 0.0f};
    #pragma unroll
    for (int t = 0; t < 4; ++t) {
        const int k0 = 2 * t, k1 = 2 * t + 1;

        // D' rows k0,k1: ONE b128 each (fp16), issued early to hide latency
        half8 hd0 = *(const half8*)(D2T + cols[k0] * TSTRH + eoff);
        half8 hd1 = *(const half8*)(D2T + cols[k1] * TSTRH + eoff);

        // forward: z[i] = { y_{k0}[i], y_{k1}[i] }, y = L^-1 e_k
        v2f z[NS];
        z[k0] = (v2f){1.0f, 0.0f};
        z[k1] = (v2f){-getel2(A2[k1], k0), 1.0f};
        #pragma unroll
        for (int i = k1 + 1; i < NS; ++i) {
            v2f a = (v2f){0.0f, 0.0f};
            #pragma unroll
            for (int j = k0; j < i; ++j)
                a = pkfma(bc2(getel2(A2[i], j)), z[j], a);
            z[i] = -a;
        }

        // back (in place): U x = y, x stored over z
        #pragma unroll
        for (int i = NS - 1; i >= 0; --i) {
            v2f a = (i >= k0) ? z[i] : (v2f){0.0f, 0.0f};
            #pragma unroll
            for (int c2 = i + 1; c2 < NS; ++c2)
                a = pkfma(-bc2(getel2(A2[i], c2)), z[c2], a);
            z[i] = a * bc2(getel2(A2[i], i));
        }

        // packed dot: acc2 += (x_k0[i], x_k1[i]) * (D'_k0[i], D'_k1[i])
        #pragma unroll
        for (int i = 0; i < NS; ++i)
            acc2 = pkfma(z[i], (v2f){(float)hd0[i], (float)hd1[i]}, acc2);
    }

    det_out = det;
    tr_out  = acc2.x + acc2.y;
}

// Block = 256 threads = 4 spin-pure waves: w0=(b0,up) w1=(b0,dn) w2=(b1,up)
// w3=(b1,dn); lane = config index. launch_bounds(256,4) pins 4 waves/SIMD
// (VGPR cap 128) — the occupancy cliff is the R14 lever.
__global__ __launch_bounds__(256, 4)
void kp_dh_kernel(const float* __restrict__ MO,
                  const float* __restrict__ d2MO,
                  const int*   __restrict__ cfg_up,
                  const int*   __restrict__ cfg_dn,
                  float*       __restrict__ out)
{
    __shared__ float    smemA[2][TSZ];       // [batch-half][MO^T fp32, 32 x 20]
    __shared__ _Float16 smemD[2][TSZH];      // [batch-half][d2MO^T fp16, 32 x 24]
    __shared__ float    xtr [2][NCONF];      // dn -> up exchange
    __shared__ float    xdet[2][NCONF];

    const int tid  = threadIdx.x;
    const int half = tid >> 7;               // batch within block (0/1)
    const int u    = tid & 127;              // id within the batch's 128 threads
    const int b    = blockIdx.x * 2 + half;  // batch index

    float*    MOT = smemA[half];
    _Float16* D2T = smemD[half];

    const float* MOb = MO   + (size_t)b * NELEC * NMO;
    const float* d2b = d2MO + (size_t)b * NELEC * NMO;

    // Stage MO^T (fp32) and d2MO^T (fp16): column-quad per thread.
    // Global: 4 scalar dwords per array; for fixed quad-row the 32 lanes of
    // an r0-group cover 32 consecutive dwords -> 2x128B segments per instr.
    // LDS: one b128 (A) + one b64 (D) per thread (uniform bank spread),
    // replacing the old 8 conflicted b32/b16 scatter writes.
    {
        const int c  = u & 31;               // mo column
        const int r0 = (u >> 5) << 2;        // electron quad base {0,4,8,12}
        const float* pa = MOb + r0 * NMO + c;
        const float* pd = d2b + r0 * NMO + c;
        float a0 = pa[0 * NMO], a1 = pa[1 * NMO], a2 = pa[2 * NMO], a3 = pa[3 * NMO];
        float d0 = pd[0 * NMO], d1 = pd[1 * NMO], d2 = pd[2 * NMO], d3 = pd[3 * NMO];
        *(float4*)(MOT + c * TSTR + r0) = make_float4(a0, a1, a2, a3);
        *(half4*)(D2T + c * TSTRH + r0) =
            (half4){(_Float16)d0, (_Float16)d1, (_Float16)d2, (_Float16)d3};
    }

    // Per-thread config load (unsorted — R13 proved the sort neutral).
    const int s    = (tid >> 6) & 1;         // 0 = up wave, 1 = dn wave
    const int cidx = tid & 63;               // config index = lane
    const int* cfg = s ? cfg_dn : cfg_up;
    int4 q0 = ((const int4*)cfg)[cidx * 2 + 0];
    int4 q1 = ((const int4*)cfg)[cidx * 2 + 1];
    const int cols[NS] = {q0.x, q0.y, q0.z, q0.w, q1.x, q1.y, q1.z, q1.w};

    __syncthreads();

    float det, tr;
    solve8T(MOT, D2T, cols, s * NS, det, tr);

    // spin combine: dn waves publish, up waves finalize (coalesced store)
    if (s) { xtr[half][cidx] = tr; xdet[half][cidx] = det; }
    __syncthreads();
    if (!s)
        out[(size_t)b * NCONF + cidx] =
            -0.5f * (tr + xtr[half][cidx]) * det * xdet[half][cidx];
}

extern "C" void kernel_launch(void* const* d_in, const int* in_sizes, int n_in,
                              void* d_out, int out_size, void* d_ws, size_t ws_size,
                              hipStream_t stream)
{
    const float* MO     = (const float*)d_in[0];
    const float* d2MO   = (const float*)d_in[1];
    const int*   cfg_up = (const int*)d_in[2];
    const int*   cfg_dn = (const int*)d_in[3];
    float* out = (float*)d_out;

    dim3 grid(NBATCH / 2);   // 4096 blocks, 2 batches per block
    dim3 block(256);
    kp_dh_kernel<<<grid, block, 0, stream>>>(MO, d2MO, cfg_up, cfg_dn, out);
}

// Round 3
// 88.643 us; speedup vs baseline: 1.1545x; 1.1545x over previous
//
#include <hip/hip_runtime.h>

#define NBATCH 8192
#define NELEC  16
#define NMO    32
#define NCONF  64
#define NS     8          // NUP == NDOWN == 8
#define TSTR   20         // A (fp32) row stride in floats (80 B: 16B-aligned for b128)
#define TSZ    (NMO * TSTR)
#define TSTRH  24         // D (fp16) row stride in HALVES (48 B: 16B-aligned for b128)
#define TSZH   (NMO * TSTRH)

typedef float    v2f   __attribute__((ext_vector_type(2)));
typedef _Float16 half8 __attribute__((ext_vector_type(8)));
typedef _Float16 half4 __attribute__((ext_vector_type(4)));

__device__ __forceinline__ v2f pkfma(v2f a, v2f b, v2f c) {
#if __has_builtin(__builtin_elementwise_fma)
    return __builtin_elementwise_fma(a, b, c);
#else
    return a * b + c;
#endif
}
__device__ __forceinline__ v2f bc2(float s) { return (v2f){s, s}; }
__device__ __forceinline__ float getel2(const v2f (&R)[4], int j) {
    return (j & 1) ? R[j >> 1].y : R[j >> 1].x;
}
__device__ __forceinline__ void setel2(v2f (&R)[4], int j, float v) {
    if (j & 1) R[j >> 1].y = v; else R[j >> 1].x = v;
}

// R15: occupancy, take two. Evidence ledger:
//  - R13 (DS restructure): NEUTRAL -> not DS-throughput-bound.
//  - R14 (cap 128 VGPR): -13us REGRESSION, absmax unchanged -> pure spill
//    cost; true live set > 128.
//  - Kernel never appears in top-5 (fills cap at ~44us) -> kernel ~28-31us.
//    Envelope: 89 = fill 43.5 + kernel ~28 + fixed gap ~17.
//  - Latency model: 16 waves/SIMD over kernel, ~960 issue-cyc/wave. 28us
//    only adds up at ~1 wave/SIMD (4.2k cyc/wave: ~900 global staging
//    latency vs L3 washed by the 268MB poison fill + barrier + ~2k solve
//    chains). => allocator inflated to ~256 VGPR (no occupancy request,
//    huge unrolled body) -> 1 block/CU, pure latency serialization.
// Lever: __launch_bounds__(256, 3) -> cap ~170 VGPR, comfortably above the
// audited live set (~140: A2=64, z=16, cols/addr=16, hd=4, ptrs/misc).
// 3 waves/SIMD = 3x latency hiding, zero spills expected.
// Dot reverted to R12's scalar mixed form: fmaf(x, (float)h, acc) folds to
// v_fma_mix_f32 (no explicit cvts); two accumulators halve the acc chain.
// R11/R12 numerics stand: A fp32 (fp16-A amplified by kappa -> 4e8 fail);
// D fp16 fine (enters linearly). R8: gathers stay in LDS, not global.
__device__ __forceinline__ void solve8T(const float* __restrict__ MOT,
                                        const _Float16* __restrict__ D2T,
                                        const int (&cols)[NS], int eoff,
                                        float& det_out, float& tr_out)
{
    v2f A2[NS][4];                    // row j, pair p = cols {2p, 2p+1}
    #pragma unroll
    for (int j = 0; j < NS; ++j) {
        const float4* pa = (const float4*)(MOT + cols[j] * TSTR + eoff);
        float4 a0 = pa[0], a1 = pa[1];
        A2[j][0] = (v2f){a0.x, a0.y};
        A2[j][1] = (v2f){a0.z, a0.w};
        A2[j][2] = (v2f){a1.x, a1.y};
        A2[j][3] = (v2f){a1.z, a1.w};
    }

    // In-place LU, no pivot (packed over column pairs) — byte-identical to R7.
    float det = 1.0f;
    #pragma unroll
    for (int k = 0; k < NS; ++k) {
        float ukk = getel2(A2[k], k);
        det *= ukk;
        float pinv = __builtin_amdgcn_rcpf(ukk);
        #pragma unroll
        for (int r = k + 1; r < NS; ++r) {
            float m = getel2(A2[r], k) * pinv;
            v2f m2 = bc2(m);
            #pragma unroll
            for (int p = (k + 1) >> 1; p < 4; ++p)
                A2[r][p] = pkfma(-m2, A2[k][p], A2[r][p]);
            setel2(A2[r], k, m);
        }
        setel2(A2[k], k, pinv);
    }

    // tr = sum_k <x(k), row_k(D')>, k pairs in v2f lanes. z[] holds y then x
    // in place (back-sub step i reads z[i]=y_i once before overwriting).
    float tr0 = 0.0f, tr1 = 0.0f;
    #pragma unroll
    for (int t = 0; t < 4; ++t) {
        const int k0 = 2 * t, k1 = 2 * t + 1;

        // D' rows k0,k1: ONE b128 each (fp16), issued early to hide latency
        half8 hd0 = *(const half8*)(D2T + cols[k0] * TSTRH + eoff);
        half8 hd1 = *(const half8*)(D2T + cols[k1] * TSTRH + eoff);

        // forward: z[i] = { y_{k0}[i], y_{k1}[i] }, y = L^-1 e_k
        v2f z[NS];
        z[k0] = (v2f){1.0f, 0.0f};
        z[k1] = (v2f){-getel2(A2[k1], k0), 1.0f};
        #pragma unroll
        for (int i = k1 + 1; i < NS; ++i) {
            v2f a = (v2f){0.0f, 0.0f};
            #pragma unroll
            for (int j = k0; j < i; ++j)
                a = pkfma(bc2(getel2(A2[i], j)), z[j], a);
            z[i] = -a;
        }

        // back (in place): U x = y, x stored over z
        #pragma unroll
        for (int i = NS - 1; i >= 0; --i) {
            v2f a = (i >= k0) ? z[i] : (v2f){0.0f, 0.0f};
            #pragma unroll
            for (int c2 = i + 1; c2 < NS; ++c2)
                a = pkfma(-bc2(getel2(A2[i], c2)), z[c2], a);
            z[i] = a * bc2(getel2(A2[i], i));
        }

        // mixed-precision dot: v_fma_mix_f32 folds the f16->f32 convert
        #pragma unroll
        for (int i = 0; i < NS; ++i) {
            tr0 = fmaf(z[i].x, (float)hd0[i], tr0);
            tr1 = fmaf(z[i].y, (float)hd1[i], tr1);
        }
    }

    det_out = det;
    tr_out  = tr0 + tr1;
}

// Block = 256 threads = 4 spin-pure waves: w0=(b0,up) w1=(b0,dn) w2=(b1,up)
// w3=(b1,dn); lane = config index. launch_bounds(256,3): 3 waves/SIMD
// (VGPR cap ~170 — above the ~140 live set, so no spills) vs the
// allocator's default ~256/1-wave. THE R15 lever.
__global__ __launch_bounds__(256, 3)
void kp_dh_kernel(const float* __restrict__ MO,
                  const float* __restrict__ d2MO,
                  const int*   __restrict__ cfg_up,
                  const int*   __restrict__ cfg_dn,
                  float*       __restrict__ out)
{
    __shared__ float    smemA[2][TSZ];       // [batch-half][MO^T fp32, 32 x 20]
    __shared__ _Float16 smemD[2][TSZH];      // [batch-half][d2MO^T fp16, 32 x 24]
    __shared__ float    xtr [2][NCONF];      // dn -> up exchange
    __shared__ float    xdet[2][NCONF];

    const int tid  = threadIdx.x;
    const int half = tid >> 7;               // batch within block (0/1)
    const int u    = tid & 127;              // id within the batch's 128 threads
    const int b    = blockIdx.x * 2 + half;  // batch index

    float*    MOT = smemA[half];
    _Float16* D2T = smemD[half];

    const float* MOb = MO   + (size_t)b * NELEC * NMO;
    const float* d2b = d2MO + (size_t)b * NELEC * NMO;

    // Stage MO^T (fp32) and d2MO^T (fp16): column-quad per thread.
    // Global: 4 scalar dwords per array; for fixed quad-row the 32 lanes of
    // an r0-group cover 32 consecutive dwords -> 2x128B segments per instr.
    // LDS: one b128 (A) + one b64 (D) per thread (uniform bank spread).
    {
        const int c  = u & 31;               // mo column
        const int r0 = (u >> 5) << 2;        // electron quad base {0,4,8,12}
        const float* pa = MOb + r0 * NMO + c;
        const float* pd = d2b + r0 * NMO + c;
        float a0 = pa[0 * NMO], a1 = pa[1 * NMO], a2 = pa[2 * NMO], a3 = pa[3 * NMO];
        float d0 = pd[0 * NMO], d1 = pd[1 * NMO], d2 = pd[2 * NMO], d3 = pd[3 * NMO];
        *(float4*)(MOT + c * TSTR + r0) = make_float4(a0, a1, a2, a3);
        *(half4*)(D2T + c * TSTRH + r0) =
            (half4){(_Float16)d0, (_Float16)d1, (_Float16)d2, (_Float16)d3};
    }

    // Per-thread config load (unsorted — R13 proved the sort neutral).
    const int s    = (tid >> 6) & 1;         // 0 = up wave, 1 = dn wave
    const int cidx = tid & 63;               // config index = lane
    const int* cfg = s ? cfg_dn : cfg_up;
    int4 q0 = ((const int4*)cfg)[cidx * 2 + 0];
    int4 q1 = ((const int4*)cfg)[cidx * 2 + 1];
    const int cols[NS] = {q0.x, q0.y, q0.z, q0.w, q1.x, q1.y, q1.z, q1.w};

    __syncthreads();

    float det, tr;
    solve8T(MOT, D2T, cols, s * NS, det, tr);

    // spin combine: dn waves publish, up waves finalize (coalesced store)
    if (s) { xtr[half][cidx] = tr; xdet[half][cidx] = det; }
    __syncthreads();
    if (!s)
        out[(size_t)b * NCONF + cidx] =
            -0.5f * (tr + xtr[half][cidx]) * det * xdet[half][cidx];
}

extern "C" void kernel_launch(void* const* d_in, const int* in_sizes, int n_in,
                              void* d_out, int out_size, void* d_ws, size_t ws_size,
                              hipStream_t stream)
{
    const float* MO     = (const float*)d_in[0];
    const float* d2MO   = (const float*)d_in[1];
    const int*   cfg_up = (const int*)d_in[2];
    const int*   cfg_dn = (const int*)d_in[3];
    float* out = (float*)d_out;

    dim3 grid(NBATCH / 2);   // 4096 blocks, 2 batches per block
    dim3 block(256);
    kp_dh_kernel<<<grid, block, 0, stream>>>(MO, d2MO, cfg_up, cfg_dn, out);
}